// Round 5
// baseline (90.063 us; speedup 1.0000x reference)
//
#include <hip/hip_runtime.h>

// PewLSTM HS=1, quad-systolic: 4 lanes per sequence.
// Lane roles within a quad: 0 = L1·gates(i,f), 1 = L1·gates(g,o),
//                           2 = L2·gates(i,f), 3 = L2·gates(g,o).
// Layer 2 lags layer 1 by one step (systolic); gate halves exchanged via DPP
// quad_perm. 32768 seqs x 4 lanes = 2048 waves = 2 waves/SIMD (TLP fills the
// in-order chain stalls that capped the 2-lane version at ~460 cy/step).
// Weights pre-scaled by -log2e (-2log2e for tanh gate); fused-rational c/h.

constexpr int BB  = 32768;
constexpr int TT  = 168;
constexpr int CHS = 8;            // timesteps per chunk
constexpr int CHV = 10;           // float4 per chunk
constexpr int NCH = 21;           // chunks

#define LOG2E  1.44269504088896341f
#define NEG2L  (-2.88539008177792681f)
#define ACLAMP 40.0f              // exp2-arg clamp (den <= 2^120)

__device__ __forceinline__ float dpp_pull(float x) {   // quad_perm(1,0,3,2)
    return __int_as_float(__builtin_amdgcn_mov_dpp(__float_as_int(x), 0xB1, 0xF, 0xF, true));
}
__device__ __forceinline__ float dpp_bA(float x) {     // quad_perm(0,0,2,2): own layer's A lane
    return __int_as_float(__builtin_amdgcn_mov_dpp(__float_as_int(x), 0xA0, 0xF, 0xF, true));
}
__device__ __forceinline__ float dpp_b0(float x) {     // quad_perm(0,0,0,0): L1A lane
    return __int_as_float(__builtin_amdgcn_mov_dpp(__float_as_int(x), 0x00, 0xF, 0xF, true));
}

__global__ __launch_bounds__(64, 2) void pewlstm_kernel(
    const float* __restrict__ in,
    const float* __restrict__ W1ih, const float* __restrict__ W1hh,
    const float* __restrict__ W1wh, const float* __restrict__ b1,
    const float* __restrict__ W2ih, const float* __restrict__ W2hh,
    const float* __restrict__ W2wh, const float* __restrict__ b2,
    const float* __restrict__ fcw, const float* __restrict__ fcb,
    float* __restrict__ out)
{
    const int tid = blockIdx.x * 64 + threadIdx.x;
    const int q   = tid >> 2;            // sequence index
    const int r   = tid & 3;             // quad role
    const int l2  = r >> 1;              // layer-2 flag
    const int go  = (r & 1) * 2;         // my low gate (0 or 2)
    const float l2f = l2 ? 1.0f : 0.0f;

    const float* Wih = l2 ? W2ih : W1ih;
    const float* Whh = l2 ? W2hh : W1hh;
    const float* Wwh = l2 ? W2wh : W1wh;
    const float* Bv  = l2 ? b2   : b1;

    // gate order [i,f,g,o]; tanh gate (2) scaled by -2log2e, others by -log2e
    const float sLo = (go == 2) ? NEG2L : -LOG2E;
    const float sHi = -LOG2E;
    const float wihLo = Wih[go] * sLo,  wihHi = Wih[go + 1] * sHi;
    const float whhLo = Whh[go] * sLo,  whhHi = Whh[go + 1] * sHi;
    const float bLo   = Bv[go]  * sLo,  bHi   = Bv[go + 1]  * sHi;
    float wwLo[4], wwHi[4];
#pragma unroll
    for (int w = 0; w < 4; ++w) {
        wwLo[w] = Wwh[w * 4 + go]     * sLo;
        wwHi[w] = Wwh[w * 4 + go + 1] * sHi;
    }
    const float fw = fcw[0], fbv = fcb[0];

    const float4* __restrict__ row =
        reinterpret_cast<const float4*>(in + (size_t)q * (TT * 5));
    float4* orow = reinterpret_cast<float4*>(out + (size_t)q * TT);

    float4 pref[CHV];
#pragma unroll
    for (int i = 0; i < CHV; ++i) pref[i] = row[i];   // chunk 0

    float h = 0.f, cc = 0.f, h1x = 0.f;
    float xc0 = 0.f, xc1 = 0.f, xc2 = 0.f, xc3 = 0.f;  // prev chunk's last weather
    float ob[CHS];
    float pLoA[CHS], pHiA[CHS], pLoB[CHS], pHiB[CHS];
    float cur[CHS * 5];

    auto commit = [&]() {
#pragma unroll
        for (int i = 0; i < CHV; ++i) {
            float4 v = pref[i];
            cur[4*i+0] = v.x; cur[4*i+1] = v.y;
            cur[4*i+2] = v.z; cur[4*i+3] = v.w;
        }
    };
    auto issue = [&](int c2) {
        const float4* nr = row + c2 * CHV;
#pragma unroll
        for (int i = 0; i < CHV; ++i) pref[i] = nr[i];
    };

    // x-dependent pre-activations for my 2 gates (L2 lanes use weather(t-1))
    auto build = [&](float (&pLo)[CHS], float (&pHi)[CHS]) {
#pragma unroll
        for (int s = 0; s < CHS; ++s) {
            const float w0 = l2 ? (s == 0 ? xc0 : cur[(s-1)*5+0]) : cur[s*5+0];
            const float w1 = l2 ? (s == 0 ? xc1 : cur[(s-1)*5+1]) : cur[s*5+1];
            const float w2 = l2 ? (s == 0 ? xc2 : cur[(s-1)*5+2]) : cur[s*5+2];
            const float w3 = l2 ? (s == 0 ? xc3 : cur[(s-1)*5+3]) : cur[s*5+3];
            const float xi = l2 ? 0.0f : cur[s*5+4];
            float a = bLo;
            a = fmaf(w0, wwLo[0], a); a = fmaf(w1, wwLo[1], a);
            a = fmaf(w2, wwLo[2], a); a = fmaf(w3, wwLo[3], a);
            pLo[s] = fmaf(xi, wihLo, a);
            float bb = bHi;
            bb = fmaf(w0, wwHi[0], bb); bb = fmaf(w1, wwHi[1], bb);
            bb = fmaf(w2, wwHi[2], bb); bb = fmaf(w3, wwHi[3], bb);
            pHi[s] = fmaf(xi, wihHi, bb);
        }
        xc0 = cur[35]; xc1 = cur[36]; xc2 = cur[37]; xc3 = cur[38];
    };

    auto phase2 = [&](float (&pLo)[CHS], float (&pHi)[CHS], int c, bool is0) {
#pragma unroll
        for (int s = 0; s < CHS; ++s) {
            const float inv = h1x * l2f;                 // L2: h1(t-1)
            float aLo = fmaf(h, whhLo, fmaf(inv, wihLo, pLo[s]));
            float aHi = fmaf(h, whhHi, fmaf(inv, wihHi, pHi[s]));
            aLo = fminf(aLo, ACLAMP); aHi = fminf(aHi, ACLAMP);
            const float eLo = __builtin_amdgcn_exp2f(aLo);  // A: e^-ai | B: e^-2ag
            const float eHi = __builtin_amdgcn_exp2f(aHi);  // A: e^-af | B: e^-ao
            const float dLo = 1.f + eLo;
            const float dHi = 1.f + eHi;
            const float nLo = 1.f - eLo;
            // A lanes pull B's half: dG = partner dLo, nG = partner nLo, dO = partner dHi
            const float dG = dpp_pull(dLo);
            const float nG = dpp_pull(nLo);
            const float dO = dpp_pull(dHi);
            // combine (valid on A lanes; B computes garbage, overwritten by bcast)
            const float p   = dLo * dG;                  // dI*dG
            const float num = fmaf(cc, p, nG * dHi);     // dHi = dF on A
            const float den = dHi * p;
            cc = num * __builtin_amdgcn_rcpf(den);
            const float Cm = fminf(cc * NEG2L, ACLAMP);
            const float eC = __builtin_amdgcn_exp2f(Cm);
            h = (1.f - eC) * __builtin_amdgcn_rcpf(dO * (1.f + eC));

            if (s == 0 && is0) { if (l2) { h = 0.f; cc = 0.f; } }  // phantom reset

            ob[(s + 7) & 7] = fmaf(h, fw, fbv);          // valid on r==2 (L2A)

            if (s == 0 && c >= 1 && r == 2) {            // flush prev chunk
                orow[(c-1)*2+0] = make_float4(ob[0], ob[1], ob[2], ob[3]);
                orow[(c-1)*2+1] = make_float4(ob[4], ob[5], ob[6], ob[7]);
            }

            const float hb = h;
            h1x = dpp_b0(hb);      // h1(t) to all quad lanes
            h   = dpp_bA(hb);      // own layer's h to both its lanes
        }
    };

    // ---- prologue ----
    commit();
    build(pLoA, pHiA);
    issue(1);

    // ---- main: 10 x 2 chunks, ping-pong pre buffers ----
    for (int cp = 0; cp < 10; ++cp) {
        const int c0 = 2 * cp;
        commit();                        // cur = chunk c0+1
        if (c0 + 2 < NCH) issue(c0 + 2);
        build(pLoB, pHiB);
        phase2(pLoA, pHiA, c0, c0 == 0);

        commit();                        // cur = chunk c0+2
        if (c0 + 3 < NCH) issue(c0 + 3);
        build(pLoA, pHiA);
        phase2(pLoB, pHiB, c0 + 1, false);
    }

    // ---- last chunk (c=20) ----
    phase2(pLoA, pHiA, NCH - 1, false);

    // ---- epilogue step t=168: L2 computes h2(167) ----
    {
        float aLo = bLo, aHi = bHi;
        aLo = fmaf(xc0, wwLo[0], aLo); aHi = fmaf(xc0, wwHi[0], aHi);
        aLo = fmaf(xc1, wwLo[1], aLo); aHi = fmaf(xc1, wwHi[1], aHi);
        aLo = fmaf(xc2, wwLo[2], aLo); aHi = fmaf(xc2, wwHi[2], aHi);
        aLo = fmaf(xc3, wwLo[3], aLo); aHi = fmaf(xc3, wwHi[3], aHi);
        aLo = fmaf(h1x, wihLo, aLo);   aHi = fmaf(h1x, wihHi, aHi);
        aLo = fmaf(h,   whhLo, aLo);   aHi = fmaf(h,   whhHi, aHi);
        aLo = fminf(aLo, ACLAMP); aHi = fminf(aHi, ACLAMP);
        const float eLo = __builtin_amdgcn_exp2f(aLo);
        const float eHi = __builtin_amdgcn_exp2f(aHi);
        const float dLo = 1.f + eLo, dHi = 1.f + eHi, nLo = 1.f - eLo;
        const float dG = dpp_pull(dLo);
        const float nG = dpp_pull(nLo);
        const float dO = dpp_pull(dHi);
        const float p   = dLo * dG;
        const float num = fmaf(cc, p, nG * dHi);
        cc = num * __builtin_amdgcn_rcpf(dHi * p);
        const float Cm = fminf(cc * NEG2L, ACLAMP);
        const float eC = __builtin_amdgcn_exp2f(Cm);
        h = (1.f - eC) * __builtin_amdgcn_rcpf(dO * (1.f + eC));
        ob[7] = fmaf(h, fw, fbv);
        if (r == 2) {
            orow[(NCH-1)*2+0] = make_float4(ob[0], ob[1], ob[2], ob[3]);
            orow[(NCH-1)*2+1] = make_float4(ob[4], ob[5], ob[6], ob[7]);
        }
    }
}

extern "C" void kernel_launch(void* const* d_in, const int* in_sizes, int n_in,
                              void* d_out, int out_size, void* d_ws, size_t ws_size,
                              hipStream_t stream) {
    const float* in   = (const float*)d_in[0];
    const float* W1ih = (const float*)d_in[1];
    const float* W1hh = (const float*)d_in[2];
    const float* W1wh = (const float*)d_in[3];
    const float* b1   = (const float*)d_in[4];
    const float* W2ih = (const float*)d_in[5];
    const float* W2hh = (const float*)d_in[6];
    const float* W2wh = (const float*)d_in[7];
    const float* b2   = (const float*)d_in[8];
    const float* fcw  = (const float*)d_in[9];
    const float* fcb  = (const float*)d_in[10];
    float* out = (float*)d_out;

    // 4 lanes/seq -> 131072 threads -> 2048 waves -> 2 waves per SIMD
    pewlstm_kernel<<<(BB * 4) / 64, 64, 0, stream>>>(
        in, W1ih, W1hh, W1wh, b1, W2ih, W2hh, W2wh, b2, fcw, fcb, out);
}

// Round 6
// 37.139 us; speedup vs baseline: 2.4250x; 2.4250x over previous
//
#include <hip/hip_runtime.h>

// PewLSTM HS=1, quad-systolic: 4 lanes per sequence, register-budgeted.
// Lane roles in a quad: 0 = L1·gates(i,f), 1 = L1·gates(g,o),
//                       2 = L2·gates(i,f), 3 = L2·gates(g,o).
// Layer 2 lags layer 1 by one step; halves exchanged via DPP quad_perm.
// 32768 seqs x 4 lanes = 2048 waves = 2 waves/SIMD (TLP hides chain stalls).
// R5 change vs R4: no pre-activation buffers (fused into step), only the
// float4 prefetch is double-buffered -> ~120 VGPRs, no scratch spill.

constexpr int BB  = 32768;
constexpr int TT  = 168;
constexpr int CHS = 8;            // timesteps per chunk
constexpr int CHV = 10;           // float4 per chunk
constexpr int NCH = 21;           // chunks

#define LOG2E  1.44269504088896341f
#define NEG2L  (-2.88539008177792681f)
#define ACLAMP 40.0f              // exp2-arg clamp (den <= 2^120)

__device__ __forceinline__ float dpp_pull(float x) {   // quad_perm(1,0,3,2)
    return __int_as_float(__builtin_amdgcn_mov_dpp(__float_as_int(x), 0xB1, 0xF, 0xF, true));
}
__device__ __forceinline__ float dpp_bA(float x) {     // quad_perm(0,0,2,2)
    return __int_as_float(__builtin_amdgcn_mov_dpp(__float_as_int(x), 0xA0, 0xF, 0xF, true));
}
__device__ __forceinline__ float dpp_b0(float x) {     // quad_perm(0,0,0,0)
    return __int_as_float(__builtin_amdgcn_mov_dpp(__float_as_int(x), 0x00, 0xF, 0xF, true));
}

__global__ __launch_bounds__(64, 2) void pewlstm_kernel(
    const float* __restrict__ in,
    const float* __restrict__ W1ih, const float* __restrict__ W1hh,
    const float* __restrict__ W1wh, const float* __restrict__ b1,
    const float* __restrict__ W2ih, const float* __restrict__ W2hh,
    const float* __restrict__ W2wh, const float* __restrict__ b2,
    const float* __restrict__ fcw, const float* __restrict__ fcb,
    float* __restrict__ out)
{
    const int tid = blockIdx.x * 64 + threadIdx.x;
    const int q   = tid >> 2;            // sequence index
    const int r   = tid & 3;             // quad role
    const int l2  = r >> 1;              // layer-2 flag
    const int go  = (r & 1) * 2;         // my low gate (0=i,f  2=g,o)
    const float l2f = l2 ? 1.0f : 0.0f;

    const float* Wih = l2 ? W2ih : W1ih;
    const float* Whh = l2 ? W2hh : W1hh;
    const float* Wwh = l2 ? W2wh : W1wh;
    const float* Bv  = l2 ? b2   : b1;

    // gate order [i,f,g,o]; tanh gate (2) scaled by -2log2e, others by -log2e
    const float sLo = (go == 2) ? NEG2L : -LOG2E;
    const float sHi = -LOG2E;
    const float wihLo = Wih[go] * sLo,  wihHi = Wih[go + 1] * sHi;
    const float whhLo = Whh[go] * sLo,  whhHi = Whh[go + 1] * sHi;
    const float bLo   = Bv[go]  * sLo,  bHi   = Bv[go + 1]  * sHi;
    float wwLo[4], wwHi[4];
#pragma unroll
    for (int w = 0; w < 4; ++w) {
        wwLo[w] = Wwh[w * 4 + go]     * sLo;
        wwHi[w] = Wwh[w * 4 + go + 1] * sHi;
    }
    const float fw = fcw[0], fbv = fcb[0];

    const float4* __restrict__ row =
        reinterpret_cast<const float4*>(in + (size_t)q * (TT * 5));
    float4* orow = reinterpret_cast<float4*>(out + (size_t)q * TT);

    float4 bufA[CHV], bufB[CHV];
    float h = 0.f, cc = 0.f, h1x = 0.f;
    float xc0 = 0.f, xc1 = 0.f, xc2 = 0.f, xc3 = 0.f;  // prev chunk's last weather
    float ob[CHS];

    auto issue = [&](float4 (&buf)[CHV], int c2) {
#pragma unroll
        for (int i = 0; i < CHV; ++i) buf[i] = row[c2 * CHV + i];
    };

    auto process = [&](float4 (&buf)[CHV], int c, bool is0) {
        float cur[CHS * 5];
#pragma unroll
        for (int i = 0; i < CHV; ++i) {
            cur[4*i+0] = buf[i].x; cur[4*i+1] = buf[i].y;
            cur[4*i+2] = buf[i].z; cur[4*i+3] = buf[i].w;
        }
#pragma unroll
        for (int s = 0; s < CHS; ++s) {
            // my step's weather/input: L1 lanes use step t, L2 lanes step t-1
            const float w0 = l2 ? (s == 0 ? xc0 : cur[(s-1)*5+0]) : cur[s*5+0];
            const float w1 = l2 ? (s == 0 ? xc1 : cur[(s-1)*5+1]) : cur[s*5+1];
            const float w2 = l2 ? (s == 0 ? xc2 : cur[(s-1)*5+2]) : cur[s*5+2];
            const float w3 = l2 ? (s == 0 ? xc3 : cur[(s-1)*5+3]) : cur[s*5+3];
            const float xi = l2 ? 0.0f : cur[s*5+4];

            // x-dependent pre-activation (independent of chain: issues early)
            float pLo = bLo, pHi = bHi;
            pLo = fmaf(w0, wwLo[0], pLo); pHi = fmaf(w0, wwHi[0], pHi);
            pLo = fmaf(w1, wwLo[1], pLo); pHi = fmaf(w1, wwHi[1], pHi);
            pLo = fmaf(w2, wwLo[2], pLo); pHi = fmaf(w2, wwHi[2], pHi);
            pLo = fmaf(w3, wwLo[3], pLo); pHi = fmaf(w3, wwHi[3], pHi);
            pLo = fmaf(xi, wihLo, pLo);   pHi = fmaf(xi, wihHi, pHi);

            // recurrent part + activations (fused-rational, 3 exp2 + 2 rcp)
            const float inv = h1x * l2f;                 // L2: h1(t-1)
            float aLo = fmaf(h, whhLo, fmaf(inv, wihLo, pLo));
            float aHi = fmaf(h, whhHi, fmaf(inv, wihHi, pHi));
            aLo = fminf(aLo, ACLAMP); aHi = fminf(aHi, ACLAMP);
            const float eLo = __builtin_amdgcn_exp2f(aLo);  // A: e^-ai | B: e^-2ag
            const float eHi = __builtin_amdgcn_exp2f(aHi);  // A: e^-af | B: e^-ao
            const float dLo = 1.f + eLo;
            const float dHi = 1.f + eHi;
            const float nLo = 1.f - eLo;
            const float dG = dpp_pull(dLo);   // partner's tanh-gate denom
            const float nG = dpp_pull(nLo);   // partner's tanh-gate numer
            const float dO = dpp_pull(dHi);   // partner's o-gate denom
            // c' = (c*dI*dG + nG*dF) / (dF*dI*dG)   (valid on A lanes)
            const float p   = dLo * dG;
            const float num = fmaf(cc, p, nG * dHi);
            cc = num * __builtin_amdgcn_rcpf(dHi * p);
            const float Cm = fminf(cc * NEG2L, ACLAMP);
            const float eC = __builtin_amdgcn_exp2f(Cm);
            h = (1.f - eC) * __builtin_amdgcn_rcpf(dO * (1.f + eC));

            if (s == 0 && is0) { if (l2) { h = 0.f; cc = 0.f; } }  // phantom reset

            ob[(s + 7) & 7] = fmaf(h, fw, fbv);          // true h2 on r==2

            if (s == 0 && c >= 1 && r == 2) {            // flush prev chunk
                orow[(c-1)*2+0] = make_float4(ob[0], ob[1], ob[2], ob[3]);
                orow[(c-1)*2+1] = make_float4(ob[4], ob[5], ob[6], ob[7]);
            }

            const float hb = h;
            h1x = dpp_b0(hb);      // h1(t) to whole quad
            h   = dpp_bA(hb);      // own layer's h to both its lanes
        }
        xc0 = cur[35]; xc1 = cur[36]; xc2 = cur[37]; xc3 = cur[38];
    };

    // ---- pipeline: A/B prefetch double-buffer ----
    issue(bufA, 0);
    for (int cp = 0; cp < 10; ++cp) {
        issue(bufB, 2 * cp + 1);
        process(bufA, 2 * cp, cp == 0);
        issue(bufA, 2 * cp + 2);          // 2cp+2 <= 20 for cp<=9
        process(bufB, 2 * cp + 1, false);
    }
    process(bufA, 20, false);

    // ---- epilogue step t=168: L2 computes h2(167) ----
    {
        float aLo = bLo, aHi = bHi;
        aLo = fmaf(xc0, wwLo[0], aLo); aHi = fmaf(xc0, wwHi[0], aHi);
        aLo = fmaf(xc1, wwLo[1], aLo); aHi = fmaf(xc1, wwHi[1], aHi);
        aLo = fmaf(xc2, wwLo[2], aLo); aHi = fmaf(xc2, wwHi[2], aHi);
        aLo = fmaf(xc3, wwLo[3], aLo); aHi = fmaf(xc3, wwHi[3], aHi);
        aLo = fmaf(h1x, wihLo, aLo);   aHi = fmaf(h1x, wihHi, aHi);
        aLo = fmaf(h,   whhLo, aLo);   aHi = fmaf(h,   whhHi, aHi);
        aLo = fminf(aLo, ACLAMP); aHi = fminf(aHi, ACLAMP);
        const float eLo = __builtin_amdgcn_exp2f(aLo);
        const float eHi = __builtin_amdgcn_exp2f(aHi);
        const float dLo = 1.f + eLo, dHi = 1.f + eHi, nLo = 1.f - eLo;
        const float dG = dpp_pull(dLo);
        const float nG = dpp_pull(nLo);
        const float dO = dpp_pull(dHi);
        const float p   = dLo * dG;
        const float num = fmaf(cc, p, nG * dHi);
        cc = num * __builtin_amdgcn_rcpf(dHi * p);
        const float Cm = fminf(cc * NEG2L, ACLAMP);
        const float eC = __builtin_amdgcn_exp2f(Cm);
        h = (1.f - eC) * __builtin_amdgcn_rcpf(dO * (1.f + eC));
        ob[7] = fmaf(h, fw, fbv);
        if (r == 2) {
            orow[(NCH-1)*2+0] = make_float4(ob[0], ob[1], ob[2], ob[3]);
            orow[(NCH-1)*2+1] = make_float4(ob[4], ob[5], ob[6], ob[7]);
        }
    }
}

extern "C" void kernel_launch(void* const* d_in, const int* in_sizes, int n_in,
                              void* d_out, int out_size, void* d_ws, size_t ws_size,
                              hipStream_t stream) {
    const float* in   = (const float*)d_in[0];
    const float* W1ih = (const float*)d_in[1];
    const float* W1hh = (const float*)d_in[2];
    const float* W1wh = (const float*)d_in[3];
    const float* b1   = (const float*)d_in[4];
    const float* W2ih = (const float*)d_in[5];
    const float* W2hh = (const float*)d_in[6];
    const float* W2wh = (const float*)d_in[7];
    const float* b2   = (const float*)d_in[8];
    const float* fcw  = (const float*)d_in[9];
    const float* fcb  = (const float*)d_in[10];
    float* out = (float*)d_out;

    // 4 lanes/seq -> 131072 threads -> 2048 waves -> 2 waves/SIMD
    pewlstm_kernel<<<(BB * 4) / 64, 64, 0, stream>>>(
        in, W1ih, W1hh, W1wh, b1, W2ih, W2hh, W2wh, b2, fcw, fcb, out);
}